// Round 4
// baseline (68.074 us; speedup 1.0000x reference)
//
#include <hip/hip_runtime.h>

// Problem constants: x[B,N], WQ/WK/WV[H,N], W0[H]; out[B,N] fp32.
#define N      4096
#define BATCH  4
#define NHEAD  4
#define DEG    12              // Taylor degree; |s*k| ~ 0.2 -> trunc err ~1e-18 rel
#define NSLOT  25              // M_1..M_12 (12) + P_0..P_12 (13)
#define BLOCK  512             // 8 waves = 4 heads x 2 j-halves
#define ITILE  128             // rows per block
#define LOG2E  1.4426950408889634f

// Rank-1 softmax attention via moment expansion (see R3), fully fused:
//   out_h[b,i] = (Nm(s_i) - e^{s_i k_i} v_i) / D(s_i),  s_i = x[b,i]*wq[i]
//   D(s)  = sum_m s^m/m! * M_m,  M_m = sum_j (x_j wk_j)^m
//   Nm(s) = sum_m s^m/m! * P_m,  P_m = sum_j (x_j wk_j)^m (x_j wv_j)
// Each block recomputes its batch's moments (cheap: 4096*4*26 fma spread over
// 8 waves, one head per wave-pair) -> no workspace, no second dispatch.
__global__ __launch_bounds__(BLOCK) void attn_fused(
    const float* __restrict__ x, const float* __restrict__ WQ,
    const float* __restrict__ WK, const float* __restrict__ WV,
    const float* __restrict__ W0, float* __restrict__ out)
{
    __shared__ float red[8][NSLOT];        // per-wave reduced moment partials
    __shared__ float cD[NHEAD][DEG + 1];   // D-poly coeffs  (M_m/m!)
    __shared__ float cP[NHEAD][DEG + 1];   // Nm-poly coeffs (P_m/m!)

    const int ntiles = N / ITILE;          // 32
    const int itile  = blockIdx.x % ntiles;
    const int b      = blockIdx.x / ntiles;

    const int wid  = threadIdx.x >> 6;     // 0..7
    const int lane = threadIdx.x & 63;
    const int h    = wid >> 1;             // head owned by this wave
    const int half = wid & 1;              // j-half owned by this wave

    const float* xb = x  + b * N;
    const float* wk = WK + h * N;
    const float* wv = WV + h * N;

    // ---- Phase 1: moments M_1..M_12, P_0..P_12 for head h over this j-half ----
    float acc[NSLOT];
    #pragma unroll
    for (int s = 0; s < NSLOT; ++s) acc[s] = 0.f;

    const int jbase = half * (N / 2);
    #pragma unroll
    for (int it = 0; it < (N / 2) / (64 * 4); ++it) {   // 8 iterations
        const int j4 = jbase + it * 256 + lane * 4;
        float4 xv = *(const float4*)(xb + j4);
        float4 kw = *(const float4*)(wk + j4);
        float4 vw = *(const float4*)(wv + j4);
        float kk[4] = {xv.x * kw.x, xv.y * kw.y, xv.z * kw.z, xv.w * kw.w};
        float vv[4] = {xv.x * vw.x, xv.y * vw.y, xv.z * vw.z, xv.w * vw.w};
        #pragma unroll
        for (int e = 0; e < 4; ++e) {
            const float k = kk[e], v = vv[e];
            acc[12] += v;                              // P_0
            float t = k;                               // running k^m
            #pragma unroll
            for (int m = 1; m <= DEG; ++m) {
                acc[m - 1] += t;                       // M_m
                acc[12 + m] = fmaf(t, v, acc[12 + m]); // P_m
                t *= k;
            }
        }
    }
    // wave butterfly reduce (64 lanes)
    #pragma unroll
    for (int off = 32; off > 0; off >>= 1) {
        #pragma unroll
        for (int s = 0; s < NSLOT; ++s) acc[s] += __shfl_xor(acc[s], off);
    }
    if (lane == 0) {
        #pragma unroll
        for (int s = 0; s < NSLOT; ++s) red[wid][s] = acc[s];
    }
    __syncthreads();

    // ---- Phase 2: combine halves, scale by 1/m! -> Horner coefficients ----
    if (threadIdx.x < NHEAD * NSLOT) {                 // threads 0..99
        const int hh = threadIdx.x / NSLOT;
        const int s  = threadIdx.x % NSLOT;
        const float val = red[2 * hh][s] + red[2 * hh + 1][s];
        constexpr float invf[DEG + 1] = {
            1.0f, 1.0f, 0.5f, 1.0f/6.0f, 1.0f/24.0f, 1.0f/120.0f, 1.0f/720.0f,
            1.0f/5040.0f, 1.0f/40320.0f, 1.0f/362880.0f, 1.0f/3628800.0f,
            1.0f/39916800.0f, 1.0f/479001600.0f};
        if (s < DEG) cD[hh][s + 1] = val * invf[s + 1];
        else         cP[hh][s - DEG] = val * invf[s - DEG];
    } else if (threadIdx.x < NHEAD * NSLOT + NHEAD) {  // threads 100..103
        cD[threadIdx.x - NHEAD * NSLOT][0] = (float)N; // M_0 = N exactly
    }
    __syncthreads();

    // ---- Phase 3: evaluate rows (threads 0..127), direct store ----
    if (threadIdx.x < ITILE) {
        const int   i  = itile * ITILE + threadIdx.x;
        const float xi = xb[i];
        float r = 0.f;
        #pragma unroll
        for (int hh = 0; hh < NHEAD; ++hh) {
            const float s  = xi * WQ[hh * N + i];
            const float ki = xi * WK[hh * N + i];
            const float vi = xi * WV[hh * N + i];
            float D = cD[hh][DEG], P = cP[hh][DEG];
            #pragma unroll
            for (int m = DEG - 1; m >= 0; --m) {
                D = fmaf(D, s, cD[hh][m]);
                P = fmaf(P, s, cP[hh][m]);
            }
            const float ei = __builtin_amdgcn_exp2f(s * ki * LOG2E); // diagonal
            r = fmaf(W0[hh], (P - ei * vi) / D, r);
        }
        out[b * N + i] = r;        // single writer: no atomics, no memset
    }
}

extern "C" void kernel_launch(void* const* d_in, const int* in_sizes, int n_in,
                              void* d_out, int out_size, void* d_ws, size_t ws_size,
                              hipStream_t stream) {
    const float* x  = (const float*)d_in[0];
    const float* WQ = (const float*)d_in[1];
    const float* WK = (const float*)d_in[2];
    const float* WV = (const float*)d_in[3];
    const float* W0 = (const float*)d_in[4];
    float* out = (float*)d_out;

    attn_fused<<<dim3(BATCH * (N / ITILE)), BLOCK, 0, stream>>>(
        x, WQ, WK, WV, W0, out);   // 128 blocks x 512 thr = 1024 waves
}